// Round 10
// baseline (2815.317 us; speedup 1.0000x reference)
//
#include <hip/hip_runtime.h>

// Problem dims
#define BB 32
#define LL 1024
#define DD 512
#define HH 8
#define DHH 64
#define DFF 2048
#define NLAYERS 6
#define AA 21
#define MTOT (BB*LL)   // 32768 rows
#define QS 1536        // qkv row stride

typedef unsigned short u16;
typedef __bf16 bf16x8 __attribute__((ext_vector_type(8)));
typedef float f32x4 __attribute__((ext_vector_type(4)));
typedef u16 u16x8 __attribute__((ext_vector_type(8)));

__device__ __forceinline__ float bf2f(u16 u) {
    return __uint_as_float(((unsigned int)u) << 16);
}
__device__ __forceinline__ u16 f2bf(float f) {
    unsigned int i = __float_as_uint(f);
    unsigned int r = i + 0x7FFFu + ((i >> 16) & 1u);
    return (u16)(r >> 16);
}

// ------- dtype detect: sample even-index u16s of tok_emb -------
__global__ void detect_kernel(const void* __restrict__ tok, int* __restrict__ flag) {
    __shared__ int cnt[256];
    int t = threadIdx.x;
    const u16* p = (const u16*)tok;
    int c = 0;
    #pragma unroll
    for (int j = 0; j < 8; j++) {
        u16 u = p[2 * (t * 8 + j)];
        int e = (u >> 7) & 0xFF;
        c += (e >= 97 && e <= 137) ? 1 : 0;
    }
    cnt[t] = c;
    __syncthreads();
    for (int s = 128; s; s >>= 1) {
        if (t < s) cnt[t] += cnt[t + s];
        __syncthreads();
    }
    if (t == 0) flag[0] = (cnt[0] > 1024) ? 1 : 0;
}

// ------- batched small-tensor convert -------
#define NTAB 13
struct ConvTab {
    const void* src[NTAB];
    unsigned long long dstOff[NTAB];
    int n[NTAB];
    int chunk[NTAB];
    int lstride[NTAB];
};
__global__ __launch_bounds__(256) void conv_small(ConvTab tab, u16* __restrict__ spBase,
                                                  const int* __restrict__ flag, int total) {
    int i = blockIdx.x * 256 + threadIdx.x;
    if (i >= total) return;
    int fl = flag[0];
    #pragma unroll 1
    for (int e = 0; e < NTAB; e++) {
        if (i < tab.n[e]) {
            const void* s = tab.src[e];
            u16 val = fl ? ((const u16*)s)[i] : f2bf(((const float*)s)[i]);
            int c = i / tab.chunk[e];
            int r = i - c * tab.chunk[e];
            spBase[tab.dstOff[e] + (size_t)c * tab.lstride[e] + r] = val;
            return;
        }
        i -= tab.n[e];
    }
}

// ------- batched convert+transpose -------
__global__ __launch_bounds__(256) void conv_T(const void* __restrict__ src,
                                              u16* __restrict__ dst, int R, int C,
                                              const int* __restrict__ flag, int dstZS) {
    __shared__ u16 tile[32][33];
    int z = blockIdx.z;
    size_t zoffS = (size_t)z * R * C;
    size_t zoffD = (size_t)z * dstZS;
    int bx = blockIdx.x * 32, by = blockIdx.y * 32;
    int tx = threadIdx.x & 31, ty = threadIdx.x >> 5;
    int fl = flag[0];
    const u16* s16 = (const u16*)src + zoffS;
    const float* s32 = (const float*)src + zoffS;
    #pragma unroll
    for (int r = 0; r < 4; r++) {
        size_t idx = (size_t)(by + ty * 4 + r) * C + bx + tx;
        tile[ty * 4 + r][tx] = fl ? s16[idx] : f2bf(s32[idx]);
    }
    __syncthreads();
    #pragma unroll
    for (int r = 0; r < 4; r++)
        dst[zoffD + (size_t)(bx + ty * 4 + r) * R + by + tx] = tile[tx][ty * 4 + r];
}

// ------- wout pad -------
__global__ __launch_bounds__(256) void woutpad_kernel(const void* __restrict__ wout,
                                                      const void* __restrict__ bout,
                                                      u16* __restrict__ wpad,
                                                      u16* __restrict__ bpad,
                                                      const int* __restrict__ flag) {
    int i = blockIdx.x * 256 + threadIdx.x;
    int fl = flag[0];
    if (i < 128 * 512) {
        int n = i >> 9, kk = i & 511;
        u16 val = 0;
        if (n < AA) val = fl ? ((const u16*)wout)[kk * AA + n] : f2bf(((const float*)wout)[kk * AA + n]);
        wpad[(size_t)n * 512 + kk] = val;
    }
    if (i < 128) {
        u16 val = 0;
        if (i < AA) val = fl ? ((const u16*)bout)[i] : f2bf(((const float*)bout)[i]);
        bpad[i] = val;
    }
}

// ---------------- embed (bf16 residual) ----------------
__global__ __launch_bounds__(128) void embed_kernel(const int* __restrict__ x,
                                                    const u16* __restrict__ tok_emb,
                                                    const u16* __restrict__ pos_emb,
                                                    u16* __restrict__ h) {
    int row = blockIdx.x;
    int l = row & (LL - 1);
    int tok = x[row];
    int c = threadIdx.x * 4;
    ushort4 te = *(const ushort4*)(tok_emb + (size_t)tok * DD + c);
    ushort4 pe = *(const ushort4*)(pos_emb + (size_t)l * DD + c);
    ushort4 o;
    o.x = f2bf(bf2f(te.x) + bf2f(pe.x));
    o.y = f2bf(bf2f(te.y) + bf2f(pe.y));
    o.z = f2bf(bf2f(te.z) + bf2f(pe.z));
    o.w = f2bf(bf2f(te.w) + bf2f(pe.w));
    *(ushort4*)(h + (size_t)row * DD + c) = o;
}

// ---------------- LayerNorm (bf16 residual in, bf16 out) ----------------
__global__ __launch_bounds__(256) void ln_kernel(const u16* __restrict__ h,
                                                 const u16* __restrict__ s,
                                                 const u16* __restrict__ b,
                                                 u16* __restrict__ outp) {
    int row = blockIdx.x * 4 + (threadIdx.x >> 6);
    int lane = threadIdx.x & 63;
    u16x8 hv = *(const u16x8*)(h + (size_t)row * DD + lane * 8);
    float v[8];
    #pragma unroll
    for (int i = 0; i < 8; i++) v[i] = bf2f(hv[i]);
    float sum = v[0]+v[1]+v[2]+v[3]+v[4]+v[5]+v[6]+v[7];
    #pragma unroll
    for (int off = 32; off; off >>= 1) sum += __shfl_xor(sum, off, 64);
    float mu = sum * (1.0f / DD);
    float var = 0.f;
    #pragma unroll
    for (int i = 0; i < 8; i++) {
        float d = v[i] - mu;
        var += d * d;
    }
    #pragma unroll
    for (int off = 32; off; off >>= 1) var += __shfl_xor(var, off, 64);
    float rs = rsqrtf(var * (1.0f / DD) + 1e-6f);
    u16x8 sv = *(const u16x8*)(s + lane * 8);
    u16x8 bv = *(const u16x8*)(b + lane * 8);
    u16x8 o;
    #pragma unroll
    for (int i = 0; i < 8; i++)
        o[i] = f2bf((v[i] - mu) * rs * bf2f(sv[i]) + bf2f(bv[i]));
    *(u16x8*)(outp + (size_t)row * DD + lane * 8) = o;
}

#define GLD16(gp, lp) __builtin_amdgcn_global_load_lds( \
    (const __attribute__((address_space(1))) void*)(gp), \
    (__attribute__((address_space(3))) void*)(lp), 16, 0, 0)
#define WAIT_VM(n) asm volatile("s_waitcnt vmcnt(" #n ") lgkmcnt(0)" ::: "memory")

// ---------------- legacy 128x128 2ph GEMM (logits matmul, N=128) ----------------
template <int EPI>
__global__ __launch_bounds__(256) void gemm_bt(const u16* __restrict__ A,
                                               const u16* __restrict__ BT,
                                               const u16* __restrict__ bias,
                                               u16* __restrict__ Cb,
                                               float* __restrict__ Cf,
                                               int M, int N, int K, int lda,
                                               const int* __restrict__ flag) {
    __shared__ __align__(16) u16 Als[2][128 * 32];
    __shared__ __align__(16) u16 Bls[2][128 * 32];
    const int tid  = threadIdx.x;
    const int lane = tid & 63;
    const int wave = tid >> 6;

    int gx = gridDim.x, gy = gridDim.y;
    int tileX, tileY;
    if ((gy & 7) == 0) {
        int bid = blockIdx.y * gx + blockIdx.x;
        int xcd = bid & 7;
        int idx = bid >> 3;
        int stripe = gy >> 3;
        tileX = idx % gx;
        tileY = xcd * stripe + idx / gx;
    } else {
        tileX = blockIdx.x; tileY = blockIdx.y;
    }
    const int tileM = tileY * 128;
    const int tileN = tileX * 128;
    const int wm = (wave & 1) * 64;
    const int wn = (wave >> 1) * 64;

    const int srow = tid >> 2;
    const int scol = (((tid & 3) ^ ((tid >> 3) & 3))) * 8;

    const u16* Ag0 = A  + (size_t)(tileM + srow) * lda + scol;
    const u16* Ag1 = A  + (size_t)(tileM + 64 + srow) * lda + scol;
    const u16* Bg0 = BT + (size_t)(tileN + srow) * K + scol;
    const u16* Bg1 = BT + (size_t)(tileN + 64 + srow) * K + scol;

    f32x4 acc[4][4] = {};
    const int lm = lane & 15;
    const int lk = (((lane >> 4) ^ ((lm >> 1) & 3))) * 8;

    const int nk = K >> 5;
    GLD16(Ag0, Als[0] + tid * 8);
    GLD16(Ag1, Als[0] + 2048 + tid * 8);
    GLD16(Bg0, Bls[0] + tid * 8);
    GLD16(Bg1, Bls[0] + 2048 + tid * 8);
    __syncthreads();

    for (int kt = 0; kt < nk; kt++) {
        const int cur = kt & 1;
        const int nxt = cur ^ 1;
        if (kt + 1 < nk) {
            const int k1 = (kt + 1) << 5;
            GLD16(Ag0 + k1, Als[nxt] + tid * 8);
            GLD16(Ag1 + k1, Als[nxt] + 2048 + tid * 8);
            GLD16(Bg0 + k1, Bls[nxt] + tid * 8);
            GLD16(Bg1 + k1, Bls[nxt] + 2048 + tid * 8);
        }
        bf16x8 af[4], bfr[4];
        #pragma unroll
        for (int i = 0; i < 4; i++)
            af[i] = *(const bf16x8*)(Als[cur] + (wm + i * 16 + lm) * 32 + lk);
        #pragma unroll
        for (int j = 0; j < 4; j++)
            bfr[j] = *(const bf16x8*)(Bls[cur] + (wn + j * 16 + lm) * 32 + lk);
        #pragma unroll
        for (int i = 0; i < 4; i++)
            #pragma unroll
            for (int j = 0; j < 4; j++)
                acc[i][j] = __builtin_amdgcn_mfma_f32_16x16x32_bf16(af[i], bfr[j], acc[i][j], 0, 0, 0);
        __syncthreads();
    }

    int fl = 0;
    if constexpr (EPI == 3) fl = flag[0];
    const u16* Hb = (const u16*)Cf;
    const int r0 = (lane >> 4) * 4;
    #pragma unroll
    for (int j = 0; j < 4; j++) {
        int col = tileN + wn + j * 16 + lm;
        float bv = bf2f(bias[col]);
        #pragma unroll
        for (int i = 0; i < 4; i++) {
            int row = tileM + wm + i * 16 + r0;
            #pragma unroll
            for (int r = 0; r < 4; r++) {
                float xv = acc[i][j][r] + bv;
                if constexpr (EPI == 0) {
                    Cb[(size_t)(row + r) * N + col] = f2bf(xv);
                } else if constexpr (EPI == 1) {
                    float u = 1.5957691216057308f * (xv + 0.044715f * xv * xv * xv);
                    float t = 1.0f - 2.0f / (__expf(u) + 1.0f);
                    Cb[(size_t)(row + r) * N + col] = f2bf(0.5f * xv * (1.0f + t));
                } else if constexpr (EPI == 2) {
                    size_t idx = (size_t)(row + r) * N + col;
                    Cb[idx] = f2bf(bf2f(Cb[idx]) + xv);
                } else if constexpr (EPI == 4) {
                    size_t idx = (size_t)(row + r) * N + col;
                    Cb[idx] = f2bf(xv + bf2f(Hb[idx]));
                } else {
                    if (col < AA) {
                        size_t idx = (size_t)(row + r) * AA + col;
                        if (fl) Cb[idx] = f2bf(xv);
                        else    Cf[idx] = xv;
                    }
                }
            }
        }
    }
}

// ---------------- 8-phase 256x256 GEMM, BK=32, 3-ring, counted vmcnt ----------------
// r19: the r3 port with the drain bug FIXED. 8 waves (2M x 4N), per-wave 128x64
// (acc[8][4] -- m201 wave geometry). 3-buffer K-tile ring (96KB LDS): iter kt stages
// tile kt+2 into buf[(kt+2)%3] (never a buffer being read -> race-free by
// construction); end-of-iter wait is vmcnt(4) = "tile kt+1 landed" -- its loads got a
// FULL iteration of cover (r3's WAIT_VM(0) drained loads issued 1-3 phases earlier,
// which m218 shows = no pipeline at all). vmcnt hits 0 only at the last 2 boundaries.
// Per K-tile: 4 quadrant phases {6 ds_read_b128; 0-2 GLD; barrier; setprio(1);
// 8 MFMA; setprio(0); barrier}. Proven BK=32 XOR swizzle verbatim (conflicts 0).
// Accumulation order per acc element identical to 2ph -> absmax must be bit-equal.
template <int EPI>
__global__ __launch_bounds__(512, 2) void gemm8p(const u16* __restrict__ A,
                                                 const u16* __restrict__ BT,
                                                 const u16* __restrict__ bias,
                                                 u16* __restrict__ Cb,
                                                 float* __restrict__ Cf,
                                                 int M, int N, int K, int lda,
                                                 const int* __restrict__ flag) {
    __shared__ __align__(16) u16 Als[3][256 * 32];   // 48 KB
    __shared__ __align__(16) u16 Bls[3][256 * 32];   // 48 KB
    const int tid  = threadIdx.x;
    const int lane = tid & 63;
    const int wave = tid >> 6;
    const int wm = wave & 1;       // M half (x128)
    const int wn = wave >> 1;      // 0..3  (x64)

    int gx = gridDim.x, gy = gridDim.y;
    int tileX, tileY;
    if ((gy & 7) == 0) {
        int bid = blockIdx.y * gx + blockIdx.x;
        int xcd = bid & 7;
        int idx = bid >> 3;
        int stripe = gy >> 3;
        tileX = idx % gx;
        tileY = xcd * stripe + idx / gx;
    } else {
        tileX = blockIdx.x; tileY = blockIdx.y;
    }
    const int tileM = tileY * 256;
    const int tileN = tileX * 256;

    const int grow = tid >> 2;                               // 0..127
    const int scol = (((tid & 3) ^ ((tid >> 3) & 3))) * 8;   // proven BK=32 store swizzle
    const u16* Ag0 = A  + (size_t)(tileM + grow) * lda + scol;
    const u16* Ag1 = A  + (size_t)(tileM + 128 + grow) * lda + scol;
    const u16* Bg0 = BT + (size_t)(tileN + grow) * K + scol;
    const u16* Bg1 = BT + (size_t)(tileN + 128 + grow) * K + scol;

    f32x4 acc[8][4] = {};
    const int lm = lane & 15;
    const int lk = (((lane >> 4) ^ ((lm >> 1) & 3))) * 8;    // proven read swizzle

    const int nk = K >> 5;                                   // >= 16 at all call sites

// one quadrant phase: 6 ds_read_b128 -> staging GLDs -> barrier -> 8 MFMA
#define PH8(bb, mh, nh, ...) do {                                                   \
    const u16* Ab_ = Als[bb];                                                       \
    const u16* Bb_ = Bls[bb];                                                       \
    bf16x8 af_[4], bf_[2];                                                          \
    _Pragma("unroll")                                                               \
    for (int i = 0; i < 4; i++)                                                     \
        af_[i] = *(const bf16x8*)(Ab_ + (wm * 128 + (mh) * 64 + i * 16 + lm) * 32 + lk); \
    _Pragma("unroll")                                                               \
    for (int j = 0; j < 2; j++)                                                     \
        bf_[j] = *(const bf16x8*)(Bb_ + (wn * 64 + (nh) * 32 + j * 16 + lm) * 32 + lk);  \
    __VA_ARGS__                                                                     \
    __builtin_amdgcn_s_barrier();                                                   \
    __builtin_amdgcn_s_setprio(1);                                                  \
    _Pragma("unroll")                                                               \
    for (int i = 0; i < 4; i++)                                                     \
        _Pragma("unroll")                                                           \
        for (int j = 0; j < 2; j++)                                                 \
            acc[(mh) * 4 + i][(nh) * 2 + j] = __builtin_amdgcn_mfma_f32_16x16x32_bf16( \
                af_[i], bf_[j], acc[(mh) * 4 + i][(nh) * 2 + j], 0, 0, 0);          \
    __builtin_amdgcn_s_setprio(0);                                                  \
} while (0)

    // prologue: stage tiles 0,1; wait tile 0 (leave tile 1's 4 in flight)
    GLD16(Ag0, Als[0] + tid * 8);
    GLD16(Ag1, Als[0] + 4096 + tid * 8);
    GLD16(Bg0, Bls[0] + tid * 8);
    GLD16(Bg1, Bls[0] + 4096 + tid * 8);
    GLD16(Ag0 + 32, Als[1] + tid * 8);
    GLD16(Ag1 + 32, Als[1] + 4096 + tid * 8);
    GLD16(Bg0 + 32, Bls[1] + tid * 8);
    GLD16(Bg1 + 32, Bls[1] + 4096 + tid * 8);
    WAIT_VM(4);
    __builtin_amdgcn_s_barrier();

    int bb = 0;   // buf holding tile kt
    int b2 = 2;   // buf receiving tile kt+2
    #pragma unroll 1
    for (int kt = 0; kt < nk; kt++) {
        const bool st = (kt + 2) < nk;
        const int k2 = (kt + 2) << 5;
        PH8(bb, 0, 0, if (st) { GLD16(Ag0 + k2, Als[b2] + tid * 8);
                                GLD16(Ag1 + k2, Als[b2] + 4096 + tid * 8); });
        __builtin_amdgcn_s_barrier();
        PH8(bb, 1, 0, if (st) { GLD16(Bg0 + k2, Bls[b2] + tid * 8);
                                GLD16(Bg1 + k2, Bls[b2] + 4096 + tid * 8); });
        __builtin_amdgcn_s_barrier();
        PH8(bb, 0, 1, {});
        __builtin_amdgcn_s_barrier();
        PH8(bb, 1, 1, {});
        if (kt + 1 < nk) {
            if (st) WAIT_VM(4);   // tile kt+1 landed; tile kt+2's 4 stay in flight
            else    WAIT_VM(0);   // tail: only tile kt+1's loads remain
            __builtin_amdgcn_s_barrier();
        }
        bb = (bb == 2) ? 0 : bb + 1;
        b2 = (b2 == 2) ? 0 : b2 + 1;
    }
#undef PH8

    int fl = 0;
    if constexpr (EPI == 3) fl = flag[0];
    const u16* Hb = (const u16*)Cf;     // EPI 4: bf16 residual source
    const int r0 = (lane >> 4) * 4;     // C/D: col=lane&15, row=(lane>>4)*4+reg
    #pragma unroll
    for (int j = 0; j < 4; j++) {
        int col = tileN + wn * 64 + j * 16 + lm;
        float bv = bf2f(bias[col]);
        #pragma unroll
        for (int i = 0; i < 8; i++) {
            int row = tileM + wm * 128 + i * 16 + r0;
            #pragma unroll
            for (int r = 0; r < 4; r++) {
                float xv = acc[i][j][r] + bv;
                if constexpr (EPI == 0) {
                    Cb[(size_t)(row + r) * N + col] = f2bf(xv);
                } else if constexpr (EPI == 1) {
                    float u = 1.5957691216057308f * (xv + 0.044715f * xv * xv * xv);
                    float t = 1.0f - 2.0f / (__expf(u) + 1.0f);
                    Cb[(size_t)(row + r) * N + col] = f2bf(0.5f * xv * (1.0f + t));
                } else if constexpr (EPI == 2) {
                    size_t idx = (size_t)(row + r) * N + col;
                    Cb[idx] = f2bf(bf2f(Cb[idx]) + xv);
                } else if constexpr (EPI == 4) {
                    size_t idx = (size_t)(row + r) * N + col;
                    Cb[idx] = f2bf(xv + bf2f(Hb[idx]));
                }
            }
        }
    }
}

// ---------------- sparse attention v4: one wave per CLIQUE (4 queries share KV window) ----
__global__ __launch_bounds__(256) void attn_kernel(u16* qkv) {
    int g    = blockIdx.x * 4 + (threadIdx.x >> 6);    // clique index: b*256 + c
    int lane = threadIdx.x & 63;
    int c    = g & 255;
    int lo   = (c == 0) ? 0 : c * 4 - 4;
    int nbase = c * 4 - lo;                            // 0 (c==0) or 4
    size_t rowQ0 = (size_t)(g >> 8) * LL + c * 4;
    size_t rowK0 = (size_t)(g >> 8) * LL + lo;
    int off = lane * 8;

    u16x8 k8[8], v8[8];
    #pragma unroll
    for (int j = 0; j < 8; j++) {
        const u16* krow = qkv + (rowK0 + j) * QS;
        k8[j] = *(const u16x8*)(krow + 512 + off);
        v8[j] = *(const u16x8*)(krow + 1024 + off);
    }

    #pragma unroll
    for (int q = 0; q < 4; q++) {
        int nj = nbase + q + 1;
        size_t qrow = (rowQ0 + q) * QS;
        u16x8 q8 = *(const u16x8*)(qkv + qrow + off);
        float qf[8];
        #pragma unroll
        for (int i = 0; i < 8; i++) qf[i] = bf2f(q8[i]) * 0.125f;
        float sc[8];
        #pragma unroll
        for (int j = 0; j < 8; j++) {
            float t = 0.f;
            #pragma unroll
            for (int i = 0; i < 8; i++) t = fmaf(qf[i], bf2f(k8[j][i]), t);
            t += __shfl_xor(t, 1, 64);
            t += __shfl_xor(t, 2, 64);
            t += __shfl_xor(t, 4, 64);
            sc[j] = (j < nj) ? t : -1e30f;
        }
        float m = sc[0];
        #pragma unroll
        for (int j = 1; j < 8; j++) m = fmaxf(m, sc[j]);
        float p[8], den = 0.f;
        #pragma unroll
        for (int j = 0; j < 8; j++) { p[j] = __expf(sc[j] - m); den += p[j]; }
        float inv = 1.0f / den;
        float o[8] = {};
        #pragma unroll
        for (int j = 0; j < 8; j++)
            #pragma unroll
            for (int i = 0; i < 8; i++) o[i] = fmaf(p[j], bf2f(v8[j][i]), o[i]);
        u16x8 ov;
        #pragma unroll
        for (int i = 0; i < 8; i++) ov[i] = f2bf(o[i] * inv);
        *(u16x8*)(qkv + qrow + off) = ov;
    }
}

extern "C" void kernel_launch(void* const* d_in, const int* in_sizes, int n_in,
                              void* d_out, int out_size, void* d_ws, size_t ws_size,
                              hipStream_t stream) {
    const int base = n_in - 22;
    const int*  x    = (const int*)d_in[0];
    const void* tokI = d_in[2 + base];
    const void* posI = d_in[3 + base];
    const void* wqI  = d_in[4 + base];
    const void* bqI  = d_in[5 + base];
    const void* wkI  = d_in[6 + base];
    const void* bkI  = d_in[7 + base];
    const void* wvI  = d_in[8 + base];
    const void* bvI  = d_in[9 + base];
    const void* woI  = d_in[10 + base];
    const void* boI  = d_in[11 + base];
    const void* ln1sI = d_in[12 + base];
    const void* ln1bI = d_in[13 + base];
    const void* ln2sI = d_in[14 + base];
    const void* ln2bI = d_in[15 + base];
    const void* w1I  = d_in[16 + base];
    const void* b1I  = d_in[17 + base];
    const void* w2I  = d_in[18 + base];
    const void* b2I  = d_in[19 + base];
    const void* woutI = d_in[20 + base];
    const void* boutI = d_in[21 + base];

    // r7 layout: full-M FFN (mid 128 MB, ends exactly at wT)
    char* ws = (char*)d_ws;
    u16*  h    = (u16*)(ws + 0);                   // 32 MB bf16 residual
    u16*  hn   = (u16*)(ws + 33554432);            // 32 MB
    u16*  qkv  = (u16*)(ws + 67108864);            // qkv 96 MB / mid 128 MB
    u16*  wT   = (u16*)(ws + 201326592);           // 36 MB transposed weights
    u16*  sp   = (u16*)(ws + 239075328);           // small params
    int* flag  = (int*)(ws + 240500736);

    u16* mid = qkv;                                // 32768x2048 bf16 = 128 MB

    u16* wqkvT = wT;                               // 6 x (1536x512)
    u16* woT   = wT + 4718592;                     // 6 x (512x512)
    u16* w1T   = wT + 6291456;                     // 6 x (2048x512)
    u16* w2T   = wT + 12582912;                    // 6 x (512x2048)

    const unsigned long long oWoutPad = 0;
    const unsigned long long oBoutPad = 65536;
    const unsigned long long oTok     = 65664;
    const unsigned long long oPos     = 76416;
    const unsigned long long oQkvB    = 600704;
    const unsigned long long oBo      = 609920;
    const unsigned long long oB1      = 612992;
    const unsigned long long oB2      = 625280;
    const unsigned long long oLn1s    = 628352;
    const unsigned long long oLn1b    = 631424;
    const unsigned long long oLn2s    = 634496;
    const unsigned long long oLn2b    = 637568;

    detect_kernel<<<1, 256, 0, stream>>>(tokI, flag);

    ConvTab tab;
    const void* srcs[NTAB] = {tokI, bqI, bkI, bvI, boI, b1I, b2I, ln1sI, ln1bI, ln2sI, ln2bI, posI, tokI};
    unsigned long long offs[NTAB] = {oTok, oQkvB, oQkvB + 512, oQkvB + 1024, oBo, oB1, oB2,
                                     oLn1s, oLn1b, oLn2s, oLn2b, oPos, oTok};
    int ns[NTAB]     = {10752, 3072, 3072, 3072, 3072, 12288, 3072, 3072, 3072, 3072, 3072, 524288, 0};
    int chunks[NTAB] = {10752, 512, 512, 512, 3072, 12288, 3072, 3072, 3072, 3072, 3072, 524288, 1};
    int lstr[NTAB]   = {10752, 1536, 1536, 1536, 3072, 12288, 3072, 3072, 3072, 3072, 3072, 524288, 1};
    int total = 0;
    for (int e = 0; e < NTAB; e++) {
        tab.src[e] = srcs[e]; tab.dstOff[e] = offs[e]; tab.n[e] = ns[e];
        tab.chunk[e] = chunks[e]; tab.lstride[e] = lstr[e];
        total += ns[e];
    }
    conv_small<<<(total + 255) / 256, 256, 0, stream>>>(tab, sp, flag, total);
    woutpad_kernel<<<256, 256, 0, stream>>>(woutI, boutI, sp + oWoutPad, sp + oBoutPad, flag);

    conv_T<<<dim3(16, 16, 6), 256, 0, stream>>>(wqI, wqkvT,          DD, DD, flag, 786432);
    conv_T<<<dim3(16, 16, 6), 256, 0, stream>>>(wkI, wqkvT + 262144, DD, DD, flag, 786432);
    conv_T<<<dim3(16, 16, 6), 256, 0, stream>>>(wvI, wqkvT + 524288, DD, DD, flag, 786432);
    conv_T<<<dim3(16, 16, 6), 256, 0, stream>>>(woI, woT, DD, DD, flag, 262144);
    conv_T<<<dim3(64, 16, 6), 256, 0, stream>>>(w1I, w1T, DD, DFF, flag, 1048576);
    conv_T<<<dim3(16, 64, 6), 256, 0, stream>>>(w2I, w2T, DFF, DD, flag, 1048576);

    embed_kernel<<<MTOT, 128, 0, stream>>>(x, sp + oTok, sp + oPos, h);

    for (int l = 0; l < NLAYERS; l++) {
        u16* wqkvTl = wqkvT + (size_t)l * 786432;
        u16* woTl   = woT + (size_t)l * 262144;
        u16* w1Tl   = w1T + (size_t)l * 1048576;
        u16* w2Tl   = w2T + (size_t)l * 1048576;

        ln_kernel<<<MTOT / 4, 256, 0, stream>>>(h, sp + oLn1s + l * DD, sp + oLn1b + l * DD, hn);

        gemm8p<0><<<dim3(QS / 256, MTOT / 256), 512, 0, stream>>>(
            hn, wqkvTl, sp + oQkvB + l * QS, qkv, nullptr, MTOT, QS, DD, DD, flag);

        attn_kernel<<<MTOT / 16, 256, 0, stream>>>(qkv);

        gemm8p<2><<<dim3(DD / 256, MTOT / 256), 512, 0, stream>>>(
            qkv, woTl, sp + oBo + l * DD, h, nullptr, MTOT, DD, DD, QS, flag);

        ln_kernel<<<MTOT / 4, 256, 0, stream>>>(h, sp + oLn2s + l * DD, sp + oLn2b + l * DD, hn);

        gemm8p<1><<<dim3(DFF / 256, MTOT / 256), 512, 0, stream>>>(
            hn, w1Tl, sp + oB1 + l * DFF, mid, nullptr, MTOT, DFF, DD, DD, flag);
        if (l < NLAYERS - 1) {
            gemm8p<2><<<dim3(DD / 256, MTOT / 256), 512, 0, stream>>>(
                mid, w2Tl, sp + oB2 + l * DD, h, nullptr, MTOT, DD, DFF, DFF, flag);
        } else {
            gemm8p<4><<<dim3(DD / 256, MTOT / 256), 512, 0, stream>>>(
                mid, w2Tl, sp + oB2 + l * DD, hn, (float*)h, MTOT, DD, DFF, DFF, flag);
        }
    }

    gemm_bt<3><<<dim3(1, MTOT / 128), 256, 0, stream>>>(
        hn, sp + oWoutPad, sp + oBoutPad, (u16*)d_out, (float*)d_out, MTOT, 128, DD, DD, flag);
}

// Round 11
// 2538.584 us; speedup vs baseline: 1.1090x; 1.1090x over previous
//
#include <hip/hip_runtime.h>

// Problem dims
#define BB 32
#define LL 1024
#define DD 512
#define HH 8
#define DHH 64
#define DFF 2048
#define NLAYERS 6
#define AA 21
#define MTOT (BB*LL)   // 32768 rows
#define QS 1536        // qkv row stride

typedef unsigned short u16;
typedef __bf16 bf16x8 __attribute__((ext_vector_type(8)));
typedef float f32x4 __attribute__((ext_vector_type(4)));
typedef u16 u16x8 __attribute__((ext_vector_type(8)));

__device__ __forceinline__ float bf2f(u16 u) {
    return __uint_as_float(((unsigned int)u) << 16);
}
__device__ __forceinline__ u16 f2bf(float f) {
    unsigned int i = __float_as_uint(f);
    unsigned int r = i + 0x7FFFu + ((i >> 16) & 1u);
    return (u16)(r >> 16);
}

// ------- dtype detect: sample even-index u16s of tok_emb -------
__global__ void detect_kernel(const void* __restrict__ tok, int* __restrict__ flag) {
    __shared__ int cnt[256];
    int t = threadIdx.x;
    const u16* p = (const u16*)tok;
    int c = 0;
    #pragma unroll
    for (int j = 0; j < 8; j++) {
        u16 u = p[2 * (t * 8 + j)];
        int e = (u >> 7) & 0xFF;
        c += (e >= 97 && e <= 137) ? 1 : 0;
    }
    cnt[t] = c;
    __syncthreads();
    for (int s = 128; s; s >>= 1) {
        if (t < s) cnt[t] += cnt[t + s];
        __syncthreads();
    }
    if (t == 0) flag[0] = (cnt[0] > 1024) ? 1 : 0;
}

// ------- batched small-tensor convert -------
#define NTAB 13
struct ConvTab {
    const void* src[NTAB];
    unsigned long long dstOff[NTAB];
    int n[NTAB];
    int chunk[NTAB];
    int lstride[NTAB];
};
__global__ __launch_bounds__(256) void conv_small(ConvTab tab, u16* __restrict__ spBase,
                                                  const int* __restrict__ flag, int total) {
    int i = blockIdx.x * 256 + threadIdx.x;
    if (i >= total) return;
    int fl = flag[0];
    #pragma unroll 1
    for (int e = 0; e < NTAB; e++) {
        if (i < tab.n[e]) {
            const void* s = tab.src[e];
            u16 val = fl ? ((const u16*)s)[i] : f2bf(((const float*)s)[i]);
            int c = i / tab.chunk[e];
            int r = i - c * tab.chunk[e];
            spBase[tab.dstOff[e] + (size_t)c * tab.lstride[e] + r] = val;
            return;
        }
        i -= tab.n[e];
    }
}

// ------- batched convert+transpose -------
__global__ __launch_bounds__(256) void conv_T(const void* __restrict__ src,
                                              u16* __restrict__ dst, int R, int C,
                                              const int* __restrict__ flag, int dstZS) {
    __shared__ u16 tile[32][33];
    int z = blockIdx.z;
    size_t zoffS = (size_t)z * R * C;
    size_t zoffD = (size_t)z * dstZS;
    int bx = blockIdx.x * 32, by = blockIdx.y * 32;
    int tx = threadIdx.x & 31, ty = threadIdx.x >> 5;
    int fl = flag[0];
    const u16* s16 = (const u16*)src + zoffS;
    const float* s32 = (const float*)src + zoffS;
    #pragma unroll
    for (int r = 0; r < 4; r++) {
        size_t idx = (size_t)(by + ty * 4 + r) * C + bx + tx;
        tile[ty * 4 + r][tx] = fl ? s16[idx] : f2bf(s32[idx]);
    }
    __syncthreads();
    #pragma unroll
    for (int r = 0; r < 4; r++)
        dst[zoffD + (size_t)(bx + ty * 4 + r) * R + by + tx] = tile[tx][ty * 4 + r];
}

// ------- wout pad -------
__global__ __launch_bounds__(256) void woutpad_kernel(const void* __restrict__ wout,
                                                      const void* __restrict__ bout,
                                                      u16* __restrict__ wpad,
                                                      u16* __restrict__ bpad,
                                                      const int* __restrict__ flag) {
    int i = blockIdx.x * 256 + threadIdx.x;
    int fl = flag[0];
    if (i < 128 * 512) {
        int n = i >> 9, kk = i & 511;
        u16 val = 0;
        if (n < AA) val = fl ? ((const u16*)wout)[kk * AA + n] : f2bf(((const float*)wout)[kk * AA + n]);
        wpad[(size_t)n * 512 + kk] = val;
    }
    if (i < 128) {
        u16 val = 0;
        if (i < AA) val = fl ? ((const u16*)bout)[i] : f2bf(((const float*)bout)[i]);
        bpad[i] = val;
    }
}

// ---------------- embed (bf16 residual) ----------------
__global__ __launch_bounds__(128) void embed_kernel(const int* __restrict__ x,
                                                    const u16* __restrict__ tok_emb,
                                                    const u16* __restrict__ pos_emb,
                                                    u16* __restrict__ h) {
    int row = blockIdx.x;
    int l = row & (LL - 1);
    int tok = x[row];
    int c = threadIdx.x * 4;
    ushort4 te = *(const ushort4*)(tok_emb + (size_t)tok * DD + c);
    ushort4 pe = *(const ushort4*)(pos_emb + (size_t)l * DD + c);
    ushort4 o;
    o.x = f2bf(bf2f(te.x) + bf2f(pe.x));
    o.y = f2bf(bf2f(te.y) + bf2f(pe.y));
    o.z = f2bf(bf2f(te.z) + bf2f(pe.z));
    o.w = f2bf(bf2f(te.w) + bf2f(pe.w));
    *(ushort4*)(h + (size_t)row * DD + c) = o;
}

// ---------------- LayerNorm (bf16 residual in, bf16 out) ----------------
__global__ __launch_bounds__(256) void ln_kernel(const u16* __restrict__ h,
                                                 const u16* __restrict__ s,
                                                 const u16* __restrict__ b,
                                                 u16* __restrict__ outp) {
    int row = blockIdx.x * 4 + (threadIdx.x >> 6);
    int lane = threadIdx.x & 63;
    u16x8 hv = *(const u16x8*)(h + (size_t)row * DD + lane * 8);
    float v[8];
    #pragma unroll
    for (int i = 0; i < 8; i++) v[i] = bf2f(hv[i]);
    float sum = v[0]+v[1]+v[2]+v[3]+v[4]+v[5]+v[6]+v[7];
    #pragma unroll
    for (int off = 32; off; off >>= 1) sum += __shfl_xor(sum, off, 64);
    float mu = sum * (1.0f / DD);
    float var = 0.f;
    #pragma unroll
    for (int i = 0; i < 8; i++) {
        float d = v[i] - mu;
        var += d * d;
    }
    #pragma unroll
    for (int off = 32; off; off >>= 1) var += __shfl_xor(var, off, 64);
    float rs = rsqrtf(var * (1.0f / DD) + 1e-6f);
    u16x8 sv = *(const u16x8*)(s + lane * 8);
    u16x8 bv = *(const u16x8*)(b + lane * 8);
    u16x8 o;
    #pragma unroll
    for (int i = 0; i < 8; i++)
        o[i] = f2bf((v[i] - mu) * rs * bf2f(sv[i]) + bf2f(bv[i]));
    *(u16x8*)(outp + (size_t)row * DD + lane * 8) = o;
}

// ---------------- GEMM: C = A(MxK, lda) @ BT(NxK)^T + bias ----------------
// FINAL: the proven 2ph kernel (r4/r7 structure, best measured). 128x128 tile, 4 waves,
// 64x64/wave, BK=32, double-buffered, ONE barrier/iter, XOR bank swizzle (conflicts 0),
// XCD block swizzle. Residency 3 blocks/CU is load-bearing (r1/r6 ladder: 2 blocks/CU
// = -50%, 1 block/CU = collapse). 8-phase rewrites failed 3x (r1/r3/r10) -- this
// structure is the session plateau; do not grow tiles or add barriers.
// EPI 0: bf16 ; EPI 1: bf16 gelu ; EPI 2: Cb(bf16) += ; EPI 3: cols<21 dtype per flag ;
// EPI 4: bf16 out = x + bias + hres(bf16 via Cf)
#define GLD16(gp, lp) __builtin_amdgcn_global_load_lds( \
    (const __attribute__((address_space(1))) void*)(gp), \
    (__attribute__((address_space(3))) void*)(lp), 16, 0, 0)

template <int EPI>
__global__ __launch_bounds__(256) void gemm_bt(const u16* __restrict__ A,
                                               const u16* __restrict__ BT,
                                               const u16* __restrict__ bias,
                                               u16* __restrict__ Cb,
                                               float* __restrict__ Cf,
                                               int M, int N, int K, int lda,
                                               const int* __restrict__ flag) {
    __shared__ __align__(16) u16 Als[2][128 * 32];
    __shared__ __align__(16) u16 Bls[2][128 * 32];
    const int tid  = threadIdx.x;
    const int lane = tid & 63;
    const int wave = tid >> 6;

    // XCD-aware remap (xcd = linear bid % 8 on MI355X)
    int gx = gridDim.x, gy = gridDim.y;
    int tileX, tileY;
    if ((gy & 7) == 0) {
        int bid = blockIdx.y * gx + blockIdx.x;
        int xcd = bid & 7;
        int idx = bid >> 3;
        int stripe = gy >> 3;              // M-tiles per XCD
        tileX = idx % gx;                  // N fastest within XCD
        tileY = xcd * stripe + idx / gx;
    } else {
        tileX = blockIdx.x; tileY = blockIdx.y;
    }
    const int tileM = tileY * 128;
    const int tileN = tileX * 128;
    const int wm = (wave & 1) * 64;
    const int wn = (wave >> 1) * 64;

    const int srow = tid >> 2;
    const int scol = (((tid & 3) ^ ((tid >> 3) & 3))) * 8;   // swizzled k-chunk this lane fetches

    const u16* Ag0 = A  + (size_t)(tileM + srow) * lda + scol;
    const u16* Ag1 = A  + (size_t)(tileM + 64 + srow) * lda + scol;
    const u16* Bg0 = BT + (size_t)(tileN + srow) * K + scol;
    const u16* Bg1 = BT + (size_t)(tileN + 64 + srow) * K + scol;

    f32x4 acc[4][4] = {};
    const int lm = lane & 15;
    const int lk = (((lane >> 4) ^ ((lm >> 1) & 3))) * 8;    // swizzled read slot (lane-constant)

    const int nk = K >> 5;
    // prologue: stage tile 0 into buffer 0
    GLD16(Ag0, Als[0] + tid * 8);
    GLD16(Ag1, Als[0] + 2048 + tid * 8);
    GLD16(Bg0, Bls[0] + tid * 8);
    GLD16(Bg1, Bls[0] + 2048 + tid * 8);
    __syncthreads();

    for (int kt = 0; kt < nk; kt++) {
        const int cur = kt & 1;
        const int nxt = cur ^ 1;
        if (kt + 1 < nk) {
            const int k1 = (kt + 1) << 5;
            GLD16(Ag0 + k1, Als[nxt] + tid * 8);
            GLD16(Ag1 + k1, Als[nxt] + 2048 + tid * 8);
            GLD16(Bg0 + k1, Bls[nxt] + tid * 8);
            GLD16(Bg1 + k1, Bls[nxt] + 2048 + tid * 8);
        }
        bf16x8 af[4], bfr[4];
        #pragma unroll
        for (int i = 0; i < 4; i++)
            af[i] = *(const bf16x8*)(Als[cur] + (wm + i * 16 + lm) * 32 + lk);
        #pragma unroll
        for (int j = 0; j < 4; j++)
            bfr[j] = *(const bf16x8*)(Bls[cur] + (wn + j * 16 + lm) * 32 + lk);
        #pragma unroll
        for (int i = 0; i < 4; i++)
            #pragma unroll
            for (int j = 0; j < 4; j++)
                acc[i][j] = __builtin_amdgcn_mfma_f32_16x16x32_bf16(af[i], bfr[j], acc[i][j], 0, 0, 0);
        __syncthreads();   // publishes buf[nxt] (vm drain) + protects buf[cur] (lgkm drain)
    }

    int fl = 0;
    if constexpr (EPI == 3) fl = flag[0];
    const u16* Hb = (const u16*)Cf;     // EPI 4: bf16 residual source
    const int r0 = (lane >> 4) * 4;     // C/D: col=lane&15, row=(lane>>4)*4+reg
    #pragma unroll
    for (int j = 0; j < 4; j++) {
        int col = tileN + wn + j * 16 + lm;
        float bv = bf2f(bias[col]);
        #pragma unroll
        for (int i = 0; i < 4; i++) {
            int row = tileM + wm + i * 16 + r0;
            #pragma unroll
            for (int r = 0; r < 4; r++) {
                float xv = acc[i][j][r] + bv;
                if constexpr (EPI == 0) {
                    Cb[(size_t)(row + r) * N + col] = f2bf(xv);
                } else if constexpr (EPI == 1) {
                    float u = 1.5957691216057308f * (xv + 0.044715f * xv * xv * xv);
                    float t = 1.0f - 2.0f / (__expf(u) + 1.0f);
                    Cb[(size_t)(row + r) * N + col] = f2bf(0.5f * xv * (1.0f + t));
                } else if constexpr (EPI == 2) {
                    size_t idx = (size_t)(row + r) * N + col;
                    Cb[idx] = f2bf(bf2f(Cb[idx]) + xv);
                } else if constexpr (EPI == 4) {
                    size_t idx = (size_t)(row + r) * N + col;
                    Cb[idx] = f2bf(xv + bf2f(Hb[idx]));
                } else {
                    if (col < AA) {
                        size_t idx = (size_t)(row + r) * AA + col;
                        if (fl) Cb[idx] = f2bf(xv);
                        else    Cf[idx] = xv;
                    }
                }
            }
        }
    }
}

// ---------------- sparse attention v4: one wave per CLIQUE (4 queries share KV window) ----
// Junction-tree mask => query l attends exactly rows [lo..l], lo = max(0, (l&~3)-4).
// One wave loads the 8 K/V rows ONCE into registers and serves all 4 clique queries.
// Per-query arithmetic order identical to v3 (absmax-invariant, verified r7).
__global__ __launch_bounds__(256) void attn_kernel(u16* qkv) {
    int g    = blockIdx.x * 4 + (threadIdx.x >> 6);    // clique index: b*256 + c
    int lane = threadIdx.x & 63;
    int c    = g & 255;
    int lo   = (c == 0) ? 0 : c * 4 - 4;
    int nbase = c * 4 - lo;                            // 0 (c==0) or 4
    size_t rowQ0 = (size_t)(g >> 8) * LL + c * 4;
    size_t rowK0 = (size_t)(g >> 8) * LL + lo;
    int off = lane * 8;

    u16x8 k8[8], v8[8];
    #pragma unroll
    for (int j = 0; j < 8; j++) {
        const u16* krow = qkv + (rowK0 + j) * QS;      // rows lo..lo+7 always in-batch
        k8[j] = *(const u16x8*)(krow + 512 + off);
        v8[j] = *(const u16x8*)(krow + 1024 + off);
    }

    #pragma unroll
    for (int q = 0; q < 4; q++) {
        int nj = nbase + q + 1;                        // valid keys for this query
        size_t qrow = (rowQ0 + q) * QS;
        u16x8 q8 = *(const u16x8*)(qkv + qrow + off);
        float qf[8];
        #pragma unroll
        for (int i = 0; i < 8; i++) qf[i] = bf2f(q8[i]) * 0.125f;
        float sc[8];
        #pragma unroll
        for (int j = 0; j < 8; j++) {
            float t = 0.f;
            #pragma unroll
            for (int i = 0; i < 8; i++) t = fmaf(qf[i], bf2f(k8[j][i]), t);
            t += __shfl_xor(t, 1, 64);
            t += __shfl_xor(t, 2, 64);
            t += __shfl_xor(t, 4, 64);
            sc[j] = (j < nj) ? t : -1e30f;
        }
        float m = sc[0];
        #pragma unroll
        for (int j = 1; j < 8; j++) m = fmaxf(m, sc[j]);
        float p[8], den = 0.f;
        #pragma unroll
        for (int j = 0; j < 8; j++) { p[j] = __expf(sc[j] - m); den += p[j]; }
        float inv = 1.0f / den;
        float o[8] = {};
        #pragma unroll
        for (int j = 0; j < 8; j++)
            #pragma unroll
            for (int i = 0; i < 8; i++) o[i] = fmaf(p[j], bf2f(v8[j][i]), o[i]);
        u16x8 ov;
        #pragma unroll
        for (int i = 0; i < 8; i++) ov[i] = f2bf(o[i] * inv);
        *(u16x8*)(qkv + qrow + off) = ov;              // q-slot write; k/v slots untouched
    }
}

extern "C" void kernel_launch(void* const* d_in, const int* in_sizes, int n_in,
                              void* d_out, int out_size, void* d_ws, size_t ws_size,
                              hipStream_t stream) {
    const int base = n_in - 22;
    const int*  x    = (const int*)d_in[0];
    const void* tokI = d_in[2 + base];
    const void* posI = d_in[3 + base];
    const void* wqI  = d_in[4 + base];
    const void* bqI  = d_in[5 + base];
    const void* wkI  = d_in[6 + base];
    const void* bkI  = d_in[7 + base];
    const void* wvI  = d_in[8 + base];
    const void* bvI  = d_in[9 + base];
    const void* woI  = d_in[10 + base];
    const void* boI  = d_in[11 + base];
    const void* ln1sI = d_in[12 + base];
    const void* ln1bI = d_in[13 + base];
    const void* ln2sI = d_in[14 + base];
    const void* ln2bI = d_in[15 + base];
    const void* w1I  = d_in[16 + base];
    const void* b1I  = d_in[17 + base];
    const void* w2I  = d_in[18 + base];
    const void* b2I  = d_in[19 + base];
    const void* woutI = d_in[20 + base];
    const void* boutI = d_in[21 + base];

    // r7 layout (best measured: 2554us): full-M FFN, mid 128 MB ends exactly at wT.
    char* ws = (char*)d_ws;
    u16*  h    = (u16*)(ws + 0);                   // 32 MB bf16 residual
    u16*  hn   = (u16*)(ws + 33554432);            // 32 MB
    u16*  qkv  = (u16*)(ws + 67108864);            // qkv 96 MB / mid 128 MB (ends at wT)
    u16*  wT   = (u16*)(ws + 201326592);           // 36 MB transposed weights
    u16*  sp   = (u16*)(ws + 239075328);           // small params
    int* flag  = (int*)(ws + 240500736);

    u16* mid = qkv;                                // 32768x2048 bf16 = 128 MB

    u16* wqkvT = wT;                               // 6 x (1536x512)
    u16* woT   = wT + 4718592;                     // 6 x (512x512)
    u16* w1T   = wT + 6291456;                     // 6 x (2048x512)
    u16* w2T   = wT + 12582912;                    // 6 x (512x2048)

    const unsigned long long oWoutPad = 0;
    const unsigned long long oBoutPad = 65536;
    const unsigned long long oTok     = 65664;
    const unsigned long long oPos     = 76416;
    const unsigned long long oQkvB    = 600704;
    const unsigned long long oBo      = 609920;
    const unsigned long long oB1      = 612992;
    const unsigned long long oB2      = 625280;
    const unsigned long long oLn1s    = 628352;
    const unsigned long long oLn1b    = 631424;
    const unsigned long long oLn2s    = 634496;
    const unsigned long long oLn2b    = 637568;

    detect_kernel<<<1, 256, 0, stream>>>(tokI, flag);

    ConvTab tab;
    const void* srcs[NTAB] = {tokI, bqI, bkI, bvI, boI, b1I, b2I, ln1sI, ln1bI, ln2sI, ln2bI, posI, tokI};
    unsigned long long offs[NTAB] = {oTok, oQkvB, oQkvB + 512, oQkvB + 1024, oBo, oB1, oB2,
                                     oLn1s, oLn1b, oLn2s, oLn2b, oPos, oTok};
    int ns[NTAB]     = {10752, 3072, 3072, 3072, 3072, 12288, 3072, 3072, 3072, 3072, 3072, 524288, 0};
    int chunks[NTAB] = {10752, 512, 512, 512, 3072, 12288, 3072, 3072, 3072, 3072, 3072, 524288, 1};
    int lstr[NTAB]   = {10752, 1536, 1536, 1536, 3072, 12288, 3072, 3072, 3072, 3072, 3072, 524288, 1};
    int total = 0;
    for (int e = 0; e < NTAB; e++) {
        tab.src[e] = srcs[e]; tab.dstOff[e] = offs[e]; tab.n[e] = ns[e];
        tab.chunk[e] = chunks[e]; tab.lstride[e] = lstr[e];
        total += ns[e];
    }
    conv_small<<<(total + 255) / 256, 256, 0, stream>>>(tab, sp, flag, total);
    woutpad_kernel<<<256, 256, 0, stream>>>(woutI, boutI, sp + oWoutPad, sp + oBoutPad, flag);

    conv_T<<<dim3(16, 16, 6), 256, 0, stream>>>(wqI, wqkvT,          DD, DD, flag, 786432);
    conv_T<<<dim3(16, 16, 6), 256, 0, stream>>>(wkI, wqkvT + 262144, DD, DD, flag, 786432);
    conv_T<<<dim3(16, 16, 6), 256, 0, stream>>>(wvI, wqkvT + 524288, DD, DD, flag, 786432);
    conv_T<<<dim3(16, 16, 6), 256, 0, stream>>>(woI, woT, DD, DD, flag, 262144);
    conv_T<<<dim3(64, 16, 6), 256, 0, stream>>>(w1I, w1T, DD, DFF, flag, 1048576);
    conv_T<<<dim3(16, 64, 6), 256, 0, stream>>>(w2I, w2T, DFF, DD, flag, 1048576);

    embed_kernel<<<MTOT, 128, 0, stream>>>(x, sp + oTok, sp + oPos, h);

    for (int l = 0; l < NLAYERS; l++) {
        u16* wqkvTl = wqkvT + (size_t)l * 786432;
        u16* woTl   = woT + (size_t)l * 262144;
        u16* w1Tl   = w1T + (size_t)l * 1048576;
        u16* w2Tl   = w2T + (size_t)l * 1048576;

        ln_kernel<<<MTOT / 4, 256, 0, stream>>>(h, sp + oLn1s + l * DD, sp + oLn1b + l * DD, hn);

        gemm_bt<0><<<dim3(QS / 128, MTOT / 128), 256, 0, stream>>>(
            hn, wqkvTl, sp + oQkvB + l * QS, qkv, nullptr, MTOT, QS, DD, DD, flag);

        attn_kernel<<<MTOT / 16, 256, 0, stream>>>(qkv);

        gemm_bt<2><<<dim3(DD / 128, MTOT / 128), 256, 0, stream>>>(
            qkv, woTl, sp + oBo + l * DD, h, nullptr, MTOT, DD, DD, QS, flag);

        ln_kernel<<<MTOT / 4, 256, 0, stream>>>(h, sp + oLn2s + l * DD, sp + oLn2b + l * DD, hn);

        // FFN at full M (mid = 128 MB region; qkv contents already consumed by WO)
        gemm_bt<1><<<dim3(DFF / 128, MTOT / 128), 256, 0, stream>>>(
            hn, w1Tl, sp + oB1 + l * DFF, mid, nullptr, MTOT, DFF, DD, DD, flag);
        if (l < NLAYERS - 1) {
            gemm_bt<2><<<dim3(DD / 128, MTOT / 128), 256, 0, stream>>>(
                mid, w2Tl, sp + oB2 + l * DD, h, nullptr, MTOT, DD, DFF, DFF, flag);
        } else {
            gemm_bt<4><<<dim3(DD / 128, MTOT / 128), 256, 0, stream>>>(
                mid, w2Tl, sp + oB2 + l * DD, hn, (float*)h, MTOT, DD, DFF, DFF, flag);
        }
    }

    gemm_bt<3><<<dim3(1, MTOT / 128), 256, 0, stream>>>(
        hn, sp + oWoutPad, sp + oBoutPad, (u16*)d_out, (float*)d_out, MTOT, 128, DD, DD, flag);
}

// Round 12
// 2387.430 us; speedup vs baseline: 1.1792x; 1.0633x over previous
//
#include <hip/hip_runtime.h>

// Problem dims
#define BB 32
#define LL 1024
#define DD 512
#define HH 8
#define DHH 64
#define DFF 2048
#define NLAYERS 6
#define AA 21
#define MTOT (BB*LL)   // 32768 rows
#define QS 1536        // qkv row stride

typedef unsigned short u16;
typedef __bf16 bf16x8 __attribute__((ext_vector_type(8)));
typedef float f32x4 __attribute__((ext_vector_type(4)));
typedef u16 u16x8 __attribute__((ext_vector_type(8)));

__device__ __forceinline__ float bf2f(u16 u) {
    return __uint_as_float(((unsigned int)u) << 16);
}
__device__ __forceinline__ u16 f2bf(float f) {
    unsigned int i = __float_as_uint(f);
    unsigned int r = i + 0x7FFFu + ((i >> 16) & 1u);
    return (u16)(r >> 16);
}

// ------- dtype detect: sample even-index u16s of tok_emb -------
__global__ void detect_kernel(const void* __restrict__ tok, int* __restrict__ flag) {
    __shared__ int cnt[256];
    int t = threadIdx.x;
    const u16* p = (const u16*)tok;
    int c = 0;
    #pragma unroll
    for (int j = 0; j < 8; j++) {
        u16 u = p[2 * (t * 8 + j)];
        int e = (u >> 7) & 0xFF;
        c += (e >= 97 && e <= 137) ? 1 : 0;
    }
    cnt[t] = c;
    __syncthreads();
    for (int s = 128; s; s >>= 1) {
        if (t < s) cnt[t] += cnt[t + s];
        __syncthreads();
    }
    if (t == 0) flag[0] = (cnt[0] > 1024) ? 1 : 0;
}

// ------- batched small-tensor convert -------
#define NTAB 13
struct ConvTab {
    const void* src[NTAB];
    unsigned long long dstOff[NTAB];
    int n[NTAB];
    int chunk[NTAB];
    int lstride[NTAB];
};
__global__ __launch_bounds__(256) void conv_small(ConvTab tab, u16* __restrict__ spBase,
                                                  const int* __restrict__ flag, int total) {
    int i = blockIdx.x * 256 + threadIdx.x;
    if (i >= total) return;
    int fl = flag[0];
    #pragma unroll 1
    for (int e = 0; e < NTAB; e++) {
        if (i < tab.n[e]) {
            const void* s = tab.src[e];
            u16 val = fl ? ((const u16*)s)[i] : f2bf(((const float*)s)[i]);
            int c = i / tab.chunk[e];
            int r = i - c * tab.chunk[e];
            spBase[tab.dstOff[e] + (size_t)c * tab.lstride[e] + r] = val;
            return;
        }
        i -= tab.n[e];
    }
}

// ------- batched convert+transpose -------
__global__ __launch_bounds__(256) void conv_T(const void* __restrict__ src,
                                              u16* __restrict__ dst, int R, int C,
                                              const int* __restrict__ flag, int dstZS) {
    __shared__ u16 tile[32][33];
    int z = blockIdx.z;
    size_t zoffS = (size_t)z * R * C;
    size_t zoffD = (size_t)z * dstZS;
    int bx = blockIdx.x * 32, by = blockIdx.y * 32;
    int tx = threadIdx.x & 31, ty = threadIdx.x >> 5;
    int fl = flag[0];
    const u16* s16 = (const u16*)src + zoffS;
    const float* s32 = (const float*)src + zoffS;
    #pragma unroll
    for (int r = 0; r < 4; r++) {
        size_t idx = (size_t)(by + ty * 4 + r) * C + bx + tx;
        tile[ty * 4 + r][tx] = fl ? s16[idx] : f2bf(s32[idx]);
    }
    __syncthreads();
    #pragma unroll
    for (int r = 0; r < 4; r++)
        dst[zoffD + (size_t)(bx + ty * 4 + r) * R + by + tx] = tile[tx][ty * 4 + r];
}

// ------- wout pad -------
__global__ __launch_bounds__(256) void woutpad_kernel(const void* __restrict__ wout,
                                                      const void* __restrict__ bout,
                                                      u16* __restrict__ wpad,
                                                      u16* __restrict__ bpad,
                                                      const int* __restrict__ flag) {
    int i = blockIdx.x * 256 + threadIdx.x;
    int fl = flag[0];
    if (i < 128 * 512) {
        int n = i >> 9, kk = i & 511;
        u16 val = 0;
        if (n < AA) val = fl ? ((const u16*)wout)[kk * AA + n] : f2bf(((const float*)wout)[kk * AA + n]);
        wpad[(size_t)n * 512 + kk] = val;
    }
    if (i < 128) {
        u16 val = 0;
        if (i < AA) val = fl ? ((const u16*)bout)[i] : f2bf(((const float*)bout)[i]);
        bpad[i] = val;
    }
}

// ---------------- embed (bf16 residual) ----------------
__global__ __launch_bounds__(128) void embed_kernel(const int* __restrict__ x,
                                                    const u16* __restrict__ tok_emb,
                                                    const u16* __restrict__ pos_emb,
                                                    u16* __restrict__ h) {
    int row = blockIdx.x;
    int l = row & (LL - 1);
    int tok = x[row];
    int c = threadIdx.x * 4;
    ushort4 te = *(const ushort4*)(tok_emb + (size_t)tok * DD + c);
    ushort4 pe = *(const ushort4*)(pos_emb + (size_t)l * DD + c);
    ushort4 o;
    o.x = f2bf(bf2f(te.x) + bf2f(pe.x));
    o.y = f2bf(bf2f(te.y) + bf2f(pe.y));
    o.z = f2bf(bf2f(te.z) + bf2f(pe.z));
    o.w = f2bf(bf2f(te.w) + bf2f(pe.w));
    *(ushort4*)(h + (size_t)row * DD + c) = o;
}

// ---------------- LayerNorm (bf16 residual in, bf16 out) ----------------
__global__ __launch_bounds__(256) void ln_kernel(const u16* __restrict__ h,
                                                 const u16* __restrict__ s,
                                                 const u16* __restrict__ b,
                                                 u16* __restrict__ outp) {
    int row = blockIdx.x * 4 + (threadIdx.x >> 6);
    int lane = threadIdx.x & 63;
    u16x8 hv = *(const u16x8*)(h + (size_t)row * DD + lane * 8);
    float v[8];
    #pragma unroll
    for (int i = 0; i < 8; i++) v[i] = bf2f(hv[i]);
    float sum = v[0]+v[1]+v[2]+v[3]+v[4]+v[5]+v[6]+v[7];
    #pragma unroll
    for (int off = 32; off; off >>= 1) sum += __shfl_xor(sum, off, 64);
    float mu = sum * (1.0f / DD);
    float var = 0.f;
    #pragma unroll
    for (int i = 0; i < 8; i++) {
        float d = v[i] - mu;
        var += d * d;
    }
    #pragma unroll
    for (int off = 32; off; off >>= 1) var += __shfl_xor(var, off, 64);
    float rs = rsqrtf(var * (1.0f / DD) + 1e-6f);
    u16x8 sv = *(const u16x8*)(s + lane * 8);
    u16x8 bv = *(const u16x8*)(b + lane * 8);
    u16x8 o;
    #pragma unroll
    for (int i = 0; i < 8; i++)
        o[i] = f2bf((v[i] - mu) * rs * bf2f(sv[i]) + bf2f(bv[i]));
    *(u16x8*)(outp + (size_t)row * DD + lane * 8) = o;
}

// ---------------- GEMM: C = A(MxK, lda) @ BT(NxK)^T + bias ----------------
// Proven 2ph kernel (r4/r7 structure). 128x128 tile, 4 waves, 64x64/wave, BK=32,
// double-buffered, ONE barrier/iter, XOR bank swizzle (conflicts 0), XCD block swizzle.
// Residency 3 blocks/CU is load-bearing (r1/r6 ladder). Do not grow tiles.
// r20: epilogue loop order i->r->j (was j-outer). The 4 stores (and EPI2's 4 RMW
// loads) that complete one 128B cache line now issue back-to-back, so L2
// write-combining merges them: r11 counters showed WRITE amp 177/128 MB and
// write-allocate FETCH +28 MB on W1 from line-completing stores being ~48 instrs
// apart. Store addresses and per-element arithmetic bit-identical (absmax-invariant).
// EPI 0: bf16 ; EPI 1: bf16 gelu ; EPI 2: Cb(bf16) += ; EPI 3: cols<21 dtype per flag ;
// EPI 4: bf16 out = x + bias + hres(bf16 via Cf)
#define GLD16(gp, lp) __builtin_amdgcn_global_load_lds( \
    (const __attribute__((address_space(1))) void*)(gp), \
    (__attribute__((address_space(3))) void*)(lp), 16, 0, 0)

template <int EPI>
__global__ __launch_bounds__(256) void gemm_bt(const u16* __restrict__ A,
                                               const u16* __restrict__ BT,
                                               const u16* __restrict__ bias,
                                               u16* __restrict__ Cb,
                                               float* __restrict__ Cf,
                                               int M, int N, int K, int lda,
                                               const int* __restrict__ flag) {
    __shared__ __align__(16) u16 Als[2][128 * 32];
    __shared__ __align__(16) u16 Bls[2][128 * 32];
    const int tid  = threadIdx.x;
    const int lane = tid & 63;
    const int wave = tid >> 6;

    // XCD-aware remap (xcd = linear bid % 8 on MI355X)
    int gx = gridDim.x, gy = gridDim.y;
    int tileX, tileY;
    if ((gy & 7) == 0) {
        int bid = blockIdx.y * gx + blockIdx.x;
        int xcd = bid & 7;
        int idx = bid >> 3;
        int stripe = gy >> 3;              // M-tiles per XCD
        tileX = idx % gx;                  // N fastest within XCD
        tileY = xcd * stripe + idx / gx;
    } else {
        tileX = blockIdx.x; tileY = blockIdx.y;
    }
    const int tileM = tileY * 128;
    const int tileN = tileX * 128;
    const int wm = (wave & 1) * 64;
    const int wn = (wave >> 1) * 64;

    const int srow = tid >> 2;
    const int scol = (((tid & 3) ^ ((tid >> 3) & 3))) * 8;   // swizzled k-chunk this lane fetches

    const u16* Ag0 = A  + (size_t)(tileM + srow) * lda + scol;
    const u16* Ag1 = A  + (size_t)(tileM + 64 + srow) * lda + scol;
    const u16* Bg0 = BT + (size_t)(tileN + srow) * K + scol;
    const u16* Bg1 = BT + (size_t)(tileN + 64 + srow) * K + scol;

    f32x4 acc[4][4] = {};
    const int lm = lane & 15;
    const int lk = (((lane >> 4) ^ ((lm >> 1) & 3))) * 8;    // swizzled read slot (lane-constant)

    const int nk = K >> 5;
    // prologue: stage tile 0 into buffer 0
    GLD16(Ag0, Als[0] + tid * 8);
    GLD16(Ag1, Als[0] + 2048 + tid * 8);
    GLD16(Bg0, Bls[0] + tid * 8);
    GLD16(Bg1, Bls[0] + 2048 + tid * 8);
    __syncthreads();

    for (int kt = 0; kt < nk; kt++) {
        const int cur = kt & 1;
        const int nxt = cur ^ 1;
        if (kt + 1 < nk) {
            const int k1 = (kt + 1) << 5;
            GLD16(Ag0 + k1, Als[nxt] + tid * 8);
            GLD16(Ag1 + k1, Als[nxt] + 2048 + tid * 8);
            GLD16(Bg0 + k1, Bls[nxt] + tid * 8);
            GLD16(Bg1 + k1, Bls[nxt] + 2048 + tid * 8);
        }
        bf16x8 af[4], bfr[4];
        #pragma unroll
        for (int i = 0; i < 4; i++)
            af[i] = *(const bf16x8*)(Als[cur] + (wm + i * 16 + lm) * 32 + lk);
        #pragma unroll
        for (int j = 0; j < 4; j++)
            bfr[j] = *(const bf16x8*)(Bls[cur] + (wn + j * 16 + lm) * 32 + lk);
        #pragma unroll
        for (int i = 0; i < 4; i++)
            #pragma unroll
            for (int j = 0; j < 4; j++)
                acc[i][j] = __builtin_amdgcn_mfma_f32_16x16x32_bf16(af[i], bfr[j], acc[i][j], 0, 0, 0);
        __syncthreads();   // publishes buf[nxt] (vm drain) + protects buf[cur] (lgkm drain)
    }

    int fl = 0;
    if constexpr (EPI == 3) fl = flag[0];
    const u16* Hb = (const u16*)Cf;     // EPI 4: bf16 residual source
    const int r0 = (lane >> 4) * 4;     // C/D: col=lane&15, row=(lane>>4)*4+reg
    float bv[4];
    #pragma unroll
    for (int j = 0; j < 4; j++) bv[j] = bf2f(bias[tileN + wn + j * 16 + lm]);
    #pragma unroll
    for (int i = 0; i < 4; i++) {
        #pragma unroll
        for (int r = 0; r < 4; r++) {
            const int row = tileM + wm + i * 16 + r0 + r;
            const size_t rowN = (size_t)row * N;
            #pragma unroll
            for (int j = 0; j < 4; j++) {
                const int col = tileN + wn + j * 16 + lm;
                float xv = acc[i][j][r] + bv[j];
                if constexpr (EPI == 0) {
                    Cb[rowN + col] = f2bf(xv);
                } else if constexpr (EPI == 1) {
                    float u = 1.5957691216057308f * (xv + 0.044715f * xv * xv * xv);
                    float t = 1.0f - 2.0f / (__expf(u) + 1.0f);
                    Cb[rowN + col] = f2bf(0.5f * xv * (1.0f + t));
                } else if constexpr (EPI == 2) {
                    Cb[rowN + col] = f2bf(bf2f(Cb[rowN + col]) + xv);
                } else if constexpr (EPI == 4) {
                    Cb[rowN + col] = f2bf(xv + bf2f(Hb[rowN + col]));
                } else {
                    if (col < AA) {
                        size_t idx = (size_t)row * AA + col;
                        if (fl) Cb[idx] = f2bf(xv);
                        else    Cf[idx] = xv;
                    }
                }
            }
        }
    }
}

// ---------------- sparse attention v4: one wave per CLIQUE (4 queries share KV window) ----
// Junction-tree mask => query l attends exactly rows [lo..l], lo = max(0, (l&~3)-4).
// One wave loads the 8 K/V rows ONCE into registers and serves all 4 clique queries.
// Per-query arithmetic order identical to v3 (absmax-invariant, verified r7).
__global__ __launch_bounds__(256) void attn_kernel(u16* qkv) {
    int g    = blockIdx.x * 4 + (threadIdx.x >> 6);    // clique index: b*256 + c
    int lane = threadIdx.x & 63;
    int c    = g & 255;
    int lo   = (c == 0) ? 0 : c * 4 - 4;
    int nbase = c * 4 - lo;                            // 0 (c==0) or 4
    size_t rowQ0 = (size_t)(g >> 8) * LL + c * 4;
    size_t rowK0 = (size_t)(g >> 8) * LL + lo;
    int off = lane * 8;

    u16x8 k8[8], v8[8];
    #pragma unroll
    for (int j = 0; j < 8; j++) {
        const u16* krow = qkv + (rowK0 + j) * QS;      // rows lo..lo+7 always in-batch
        k8[j] = *(const u16x8*)(krow + 512 + off);
        v8[j] = *(const u16x8*)(krow + 1024 + off);
    }

    #pragma unroll
    for (int q = 0; q < 4; q++) {
        int nj = nbase + q + 1;                        // valid keys for this query
        size_t qrow = (rowQ0 + q) * QS;
        u16x8 q8 = *(const u16x8*)(qkv + qrow + off);
        float qf[8];
        #pragma unroll
        for (int i = 0; i < 8; i++) qf[i] = bf2f(q8[i]) * 0.125f;
        float sc[8];
        #pragma unroll
        for (int j = 0; j < 8; j++) {
            float t = 0.f;
            #pragma unroll
            for (int i = 0; i < 8; i++) t = fmaf(qf[i], bf2f(k8[j][i]), t);
            t += __shfl_xor(t, 1, 64);
            t += __shfl_xor(t, 2, 64);
            t += __shfl_xor(t, 4, 64);
            sc[j] = (j < nj) ? t : -1e30f;
        }
        float m = sc[0];
        #pragma unroll
        for (int j = 1; j < 8; j++) m = fmaxf(m, sc[j]);
        float p[8], den = 0.f;
        #pragma unroll
        for (int j = 0; j < 8; j++) { p[j] = __expf(sc[j] - m); den += p[j]; }
        float inv = 1.0f / den;
        float o[8] = {};
        #pragma unroll
        for (int j = 0; j < 8; j++)
            #pragma unroll
            for (int i = 0; i < 8; i++) o[i] = fmaf(p[j], bf2f(v8[j][i]), o[i]);
        u16x8 ov;
        #pragma unroll
        for (int i = 0; i < 8; i++) ov[i] = f2bf(o[i] * inv);
        *(u16x8*)(qkv + qrow + off) = ov;              // q-slot write; k/v slots untouched
    }
}

extern "C" void kernel_launch(void* const* d_in, const int* in_sizes, int n_in,
                              void* d_out, int out_size, void* d_ws, size_t ws_size,
                              hipStream_t stream) {
    const int base = n_in - 22;
    const int*  x    = (const int*)d_in[0];
    const void* tokI = d_in[2 + base];
    const void* posI = d_in[3 + base];
    const void* wqI  = d_in[4 + base];
    const void* bqI  = d_in[5 + base];
    const void* wkI  = d_in[6 + base];
    const void* bkI  = d_in[7 + base];
    const void* wvI  = d_in[8 + base];
    const void* bvI  = d_in[9 + base];
    const void* woI  = d_in[10 + base];
    const void* boI  = d_in[11 + base];
    const void* ln1sI = d_in[12 + base];
    const void* ln1bI = d_in[13 + base];
    const void* ln2sI = d_in[14 + base];
    const void* ln2bI = d_in[15 + base];
    const void* w1I  = d_in[16 + base];
    const void* b1I  = d_in[17 + base];
    const void* w2I  = d_in[18 + base];
    const void* b2I  = d_in[19 + base];
    const void* woutI = d_in[20 + base];
    const void* boutI = d_in[21 + base];

    // r7 layout (best measured): full-M FFN, mid 128 MB ends exactly at wT.
    char* ws = (char*)d_ws;
    u16*  h    = (u16*)(ws + 0);                   // 32 MB bf16 residual
    u16*  hn   = (u16*)(ws + 33554432);            // 32 MB
    u16*  qkv  = (u16*)(ws + 67108864);            // qkv 96 MB / mid 128 MB (ends at wT)
    u16*  wT   = (u16*)(ws + 201326592);           // 36 MB transposed weights
    u16*  sp   = (u16*)(ws + 239075328);           // small params
    int* flag  = (int*)(ws + 240500736);

    u16* mid = qkv;                                // 32768x2048 bf16 = 128 MB

    u16* wqkvT = wT;                               // 6 x (1536x512)
    u16* woT   = wT + 4718592;                     // 6 x (512x512)
    u16* w1T   = wT + 6291456;                     // 6 x (2048x512)
    u16* w2T   = wT + 12582912;                    // 6 x (512x2048)

    const unsigned long long oWoutPad = 0;
    const unsigned long long oBoutPad = 65536;
    const unsigned long long oTok     = 65664;
    const unsigned long long oPos     = 76416;
    const unsigned long long oQkvB    = 600704;
    const unsigned long long oBo      = 609920;
    const unsigned long long oB1      = 612992;
    const unsigned long long oB2      = 625280;
    const unsigned long long oLn1s    = 628352;
    const unsigned long long oLn1b    = 631424;
    const unsigned long long oLn2s    = 634496;
    const unsigned long long oLn2b    = 637568;

    detect_kernel<<<1, 256, 0, stream>>>(tokI, flag);

    ConvTab tab;
    const void* srcs[NTAB] = {tokI, bqI, bkI, bvI, boI, b1I, b2I, ln1sI, ln1bI, ln2sI, ln2bI, posI, tokI};
    unsigned long long offs[NTAB] = {oTok, oQkvB, oQkvB + 512, oQkvB + 1024, oBo, oB1, oB2,
                                     oLn1s, oLn1b, oLn2s, oLn2b, oPos, oTok};
    int ns[NTAB]     = {10752, 3072, 3072, 3072, 3072, 12288, 3072, 3072, 3072, 3072, 3072, 524288, 0};
    int chunks[NTAB] = {10752, 512, 512, 512, 3072, 12288, 3072, 3072, 3072, 3072, 3072, 524288, 1};
    int lstr[NTAB]   = {10752, 1536, 1536, 1536, 3072, 12288, 3072, 3072, 3072, 3072, 3072, 524288, 1};
    int total = 0;
    for (int e = 0; e < NTAB; e++) {
        tab.src[e] = srcs[e]; tab.dstOff[e] = offs[e]; tab.n[e] = ns[e];
        tab.chunk[e] = chunks[e]; tab.lstride[e] = lstr[e];
        total += ns[e];
    }
    conv_small<<<(total + 255) / 256, 256, 0, stream>>>(tab, sp, flag, total);
    woutpad_kernel<<<256, 256, 0, stream>>>(woutI, boutI, sp + oWoutPad, sp + oBoutPad, flag);

    conv_T<<<dim3(16, 16, 6), 256, 0, stream>>>(wqI, wqkvT,          DD, DD, flag, 786432);
    conv_T<<<dim3(16, 16, 6), 256, 0, stream>>>(wkI, wqkvT + 262144, DD, DD, flag, 786432);
    conv_T<<<dim3(16, 16, 6), 256, 0, stream>>>(wvI, wqkvT + 524288, DD, DD, flag, 786432);
    conv_T<<<dim3(16, 16, 6), 256, 0, stream>>>(woI, woT, DD, DD, flag, 262144);
    conv_T<<<dim3(64, 16, 6), 256, 0, stream>>>(w1I, w1T, DD, DFF, flag, 1048576);
    conv_T<<<dim3(16, 64, 6), 256, 0, stream>>>(w2I, w2T, DFF, DD, flag, 1048576);

    embed_kernel<<<MTOT, 128, 0, stream>>>(x, sp + oTok, sp + oPos, h);

    for (int l = 0; l < NLAYERS; l++) {
        u16* wqkvTl = wqkvT + (size_t)l * 786432;
        u16* woTl   = woT + (size_t)l * 262144;
        u16* w1Tl   = w1T + (size_t)l * 1048576;
        u16* w2Tl   = w2T + (size_t)l * 1048576;

        ln_kernel<<<MTOT / 4, 256, 0, stream>>>(h, sp + oLn1s + l * DD, sp + oLn1b + l * DD, hn);

        gemm_bt<0><<<dim3(QS / 128, MTOT / 128), 256, 0, stream>>>(
            hn, wqkvTl, sp + oQkvB + l * QS, qkv, nullptr, MTOT, QS, DD, DD, flag);

        attn_kernel<<<MTOT / 16, 256, 0, stream>>>(qkv);

        gemm_bt<2><<<dim3(DD / 128, MTOT / 128), 256, 0, stream>>>(
            qkv, woTl, sp + oBo + l * DD, h, nullptr, MTOT, DD, DD, QS, flag);

        ln_kernel<<<MTOT / 4, 256, 0, stream>>>(h, sp + oLn2s + l * DD, sp + oLn2b + l * DD, hn);

        // FFN at full M (mid = 128 MB region; qkv contents already consumed by WO)
        gemm_bt<1><<<dim3(DFF / 128, MTOT / 128), 256, 0, stream>>>(
            hn, w1Tl, sp + oB1 + l * DFF, mid, nullptr, MTOT, DFF, DD, DD, flag);
        if (l < NLAYERS - 1) {
            gemm_bt<2><<<dim3(DD / 128, MTOT / 128), 256, 0, stream>>>(
                mid, w2Tl, sp + oB2 + l * DD, h, nullptr, MTOT, DD, DFF, DFF, flag);
        } else {
            gemm_bt<4><<<dim3(DD / 128, MTOT / 128), 256, 0, stream>>>(
                mid, w2Tl, sp + oB2 + l * DD, hn, (float*)h, MTOT, DD, DFF, DFF, flag);
        }
    }

    gemm_bt<3><<<dim3(1, MTOT / 128), 256, 0, stream>>>(
        hn, sp + oWoutPad, sp + oBoutPad, (u16*)d_out, (float*)d_out, MTOT, 128, DD, DD, flag);
}